// Round 1
// 152.675 us; speedup vs baseline: 1.0164x; 1.0164x over previous
//
#include <hip/hip_runtime.h>

#define D 128
#define RS_STRIDE 64      // floats (256 B) between result slots

typedef __attribute__((ext_vector_type(8))) short bf16x8;
typedef __attribute__((ext_vector_type(8))) unsigned short u16x8;
typedef __attribute__((ext_vector_type(4))) float f32x4;

__device__ __forceinline__ unsigned short f2bf(float f) {
    unsigned u = __float_as_uint(f);
    unsigned r = (u + 0x7fffu + ((u >> 16) & 1u)) >> 16;
    return (unsigned short)r;
}
__device__ __forceinline__ float bf2f(unsigned short h) {
    return __uint_as_float(((unsigned)h) << 16);
}
__device__ __forceinline__ ushort4 pack4(float4 v) {
    ushort4 o; o.x = f2bf(v.x); o.y = f2bf(v.y); o.z = f2bf(v.z); o.w = f2bf(v.w);
    return o;
}
__device__ __forceinline__ void red3(float& x) {
    x += __shfl_xor(x, 8);
    x += __shfl_xor(x, 16);
    x += __shfl_xor(x, 32);
}
// LDS tile swizzle: 16B slot s (0..15) of row r -> slot s^(r&7). Keeps the
// 16-row column-slice ds_read_b128 at 2-way (free) instead of 16-way conflict.
__device__ __forceinline__ int swz(int r, int s) {
    return r * D + ((s ^ (r & 7)) << 3);     // ushort index
}

// -------------------------------------------------------------------------
// Fused prep: emb fp32->bf16 (if n4>0), W/M fp32->bf16, zero rs slots,
// and row_ptr[N+1] from sorted segment_ids (merged former rowptr_kernel).
__global__ void prep_kernel(const float* __restrict__ emb, const float* __restrict__ W,
                            const float* __restrict__ M, const int* __restrict__ seg,
                            unsigned short* __restrict__ embb,
                            unsigned short* __restrict__ Wb, unsigned short* __restrict__ Mb,
                            float* __restrict__ rs, int* __restrict__ row_ptr,
                            int n4, int E, int N) {
    int i = blockIdx.x * blockDim.x + threadIdx.x;
    if (i < n4) ((ushort4*)embb)[i] = pack4(((const float4*)emb)[i]);
    if (i < 4096)       ((ushort4*)Wb)[i]        = pack4(((const float4*)W)[i]);
    else if (i < 8192)  ((ushort4*)Mb)[i - 4096] = pack4(((const float4*)M)[i - 4096]);
    if (i < D) rs[i * RS_STRIDE] = 0.0f;
    if (i < E) {
        int s = seg[i];
        if (i == 0) {
            for (int n = 0; n <= s; ++n) row_ptr[n] = 0;
        } else {
            int sp = seg[i - 1];
            for (int n = sp + 1; n <= s; ++n) row_ptr[n] = i;
        }
        if (i == E - 1) {
            for (int n = s + 1; n <= N; ++n) row_ptr[n] = E;
        }
    }
}

// -------------------------------------------------------------------------
// Fused segment-sum + MFMA matvec + relu + column-sum. One block = one
// 16-node group. Phase A: wave w aggregates nodes 4w..4w+3 (64 lanes/node:
// 8 edge streams x 8 chunk lanes, 2x-unrolled, fp32 accum), writes agg row
// and self-emb row as bf16 into swizzled LDS tiles. Phase B: wave w computes
// dim-tiles {w, w+4}: X fragments read ONCE from LDS (was 8x global re-read),
// W/M fragments from global (L2-hot), 8 MFMAs/tile, relu, atomicAdd into rs.
// A-frag: A[m=lane&15][k=quad*8+j]; B[k][n=lane&15]=W[n][k]; C/D: col=dim,
// row=quad*4+reg (node).
__global__ __launch_bounds__(256) void fused_kernel(
    const int* __restrict__ node_ids, const int* __restrict__ nbr,
    const int* __restrict__ row_ptr, const unsigned short* __restrict__ embb,
    const unsigned short* __restrict__ Wb, const unsigned short* __restrict__ Mb,
    float* __restrict__ rs, int N) {
    __shared__ unsigned short xs[16 * D];    // self-emb rows (bf16, swizzled)
    __shared__ unsigned short as_[16 * D];   // agg rows     (bf16, swizzled)

    int t = threadIdx.x;
    int w = t >> 6;          // wave 0..3
    int tt = t & 63;
    int g = blockIdx.x;      // node group

    {   // ---- Phase A: aggregate 4 nodes per wave ----
        int c = tt & 7;      // 16B chunk 0..7 (owns chunks c and c+8)
        int j = tt >> 3;     // edge stream 0..7
        for (int i = 0; i < 4; ++i) {
            int r = w * 4 + i;           // local row 0..15
            int n = g * 16 + r;
            bool valid = n < N;

            if (j == 0) {                // self row -> xs (zeros if invalid)
                u16x8 x0 = {0, 0, 0, 0, 0, 0, 0, 0}, x1 = x0;
                if (valid) {
                    const u16x8* xr = (const u16x8*)(embb + (size_t)node_ids[n] * D);
                    x0 = xr[c]; x1 = xr[c + 8];
                }
                *(u16x8*)&xs[swz(r, c)]     = x0;
                *(u16x8*)&xs[swz(r, c + 8)] = x1;
            }

            float s0[8], s1[8];
#pragma unroll
            for (int k = 0; k < 8; ++k) { s0[k] = 0.f; s1[k] = 0.f; }

            int lo = valid ? row_ptr[n] : 0;
            int hi = valid ? row_ptr[n + 1] : 0;
            int e = lo + j;
            for (; e + 8 < hi; e += 16) {        // 2 edges in flight per lane
                const u16x8* ra = (const u16x8*)(embb + (size_t)nbr[e] * D);
                const u16x8* rb = (const u16x8*)(embb + (size_t)nbr[e + 8] * D);
                u16x8 a0 = ra[c], a1 = ra[c + 8];
                u16x8 b0 = rb[c], b1 = rb[c + 8];
#pragma unroll
                for (int k = 0; k < 8; ++k) {
                    s0[k] += bf2f(a0[k]) + bf2f(b0[k]);
                    s1[k] += bf2f(a1[k]) + bf2f(b1[k]);
                }
            }
            if (e < hi) {
                const u16x8* ra = (const u16x8*)(embb + (size_t)nbr[e] * D);
                u16x8 a0 = ra[c], a1 = ra[c + 8];
#pragma unroll
                for (int k = 0; k < 8; ++k) { s0[k] += bf2f(a0[k]); s1[k] += bf2f(a1[k]); }
            }
#pragma unroll
            for (int k = 0; k < 8; ++k) { red3(s0[k]); red3(s1[k]); }

            if (j == 0) {
                u16x8 o0, o1;
#pragma unroll
                for (int k = 0; k < 8; ++k) { o0[k] = f2bf(s0[k]); o1[k] = f2bf(s1[k]); }
                *(u16x8*)&as_[swz(r, c)]     = o0;
                *(u16x8*)&as_[swz(r, c + 8)] = o1;
            }
        }
    }
    __syncthreads();

    // ---- Phase B: matvec for dim-tiles {w, w+4} ----
    int quad = tt >> 4, col = tt & 15;
    bf16x8 ax[4], aa[4];
#pragma unroll
    for (int ks = 0; ks < 4; ++ks) {         // elements ks*32 + quad*8 .. +8
        ax[ks] = *(const bf16x8*)&xs[swz(col, ks * 4 + quad)];
        aa[ks] = *(const bf16x8*)&as_[swz(col, ks * 4 + quad)];
    }
#pragma unroll
    for (int p = 0; p < 2; ++p) {
        int dt = w + p * 4;
        int wrow = (dt * 16 + col) * D + quad * 8;
        f32x4 acc = {0.f, 0.f, 0.f, 0.f};
#pragma unroll
        for (int ks = 0; ks < 4; ++ks) {
            bf16x8 bw = *(const bf16x8*)(Wb + wrow + ks * 32);
            bf16x8 bm = *(const bf16x8*)(Mb + wrow + ks * 32);
            acc = __builtin_amdgcn_mfma_f32_16x16x32_bf16(ax[ks], bw, acc, 0, 0, 0);
            acc = __builtin_amdgcn_mfma_f32_16x16x32_bf16(aa[ks], bm, acc, 0, 0, 0);
        }
        float v = fmaxf(acc[0], 0.f) + fmaxf(acc[1], 0.f)
                + fmaxf(acc[2], 0.f) + fmaxf(acc[3], 0.f);
        v += __shfl_xor(v, 16);
        v += __shfl_xor(v, 32);
        if (tt < 16) atomicAdd(&rs[(dt * 16 + col) * RS_STRIDE], v);
    }
}

// -------------------------------------------------------------------------
// Fallback path (ws too small for bf16 emb table): unchanged proven kernels.
__global__ void agg_f32_kernel(const int* __restrict__ nbr, const int* __restrict__ row_ptr,
                               const float* __restrict__ emb,
                               unsigned short* __restrict__ aggb, int N) {
    int n = blockIdx.x * 4 + (threadIdx.x >> 6);
    if (n >= N) return;
    int tt = threadIdx.x & 63;
    int c = tt & 7;
    int j = tt >> 3;

    int lo = row_ptr[n], hi = row_ptr[n + 1];

    float4 s0 = make_float4(0.f, 0.f, 0.f, 0.f);
    float4 s1 = make_float4(0.f, 0.f, 0.f, 0.f);
    float4 s2 = make_float4(0.f, 0.f, 0.f, 0.f);
    float4 s3 = make_float4(0.f, 0.f, 0.f, 0.f);
    for (int e = lo + j; e < hi; e += 8) {
        const float4* r = (const float4*)&emb[(size_t)nbr[e] * D];
        float4 v0 = r[c], v1 = r[c + 8], v2 = r[c + 16], v3 = r[c + 24];
        s0.x += v0.x; s0.y += v0.y; s0.z += v0.z; s0.w += v0.w;
        s1.x += v1.x; s1.y += v1.y; s1.z += v1.z; s1.w += v1.w;
        s2.x += v2.x; s2.y += v2.y; s2.z += v2.z; s2.w += v2.w;
        s3.x += v3.x; s3.y += v3.y; s3.z += v3.z; s3.w += v3.w;
    }
    red3(s0.x); red3(s0.y); red3(s0.z); red3(s0.w);
    red3(s1.x); red3(s1.y); red3(s1.z); red3(s1.w);
    red3(s2.x); red3(s2.y); red3(s2.z); red3(s2.w);
    red3(s3.x); red3(s3.y); red3(s3.z); red3(s3.w);
    if (j == 0) {
        ushort4* o = (ushort4*)(aggb + (size_t)n * D);
        o[c]      = pack4(s0);
        o[c + 8]  = pack4(s1);
        o[c + 16] = pack4(s2);
        o[c + 24] = pack4(s3);
    }
}

template <bool BF>
__global__ __launch_bounds__(256) void matvec_kernel(
    const int* __restrict__ node_ids, const void* __restrict__ embv,
    const unsigned short* __restrict__ aggb,
    const unsigned short* __restrict__ Wb, const unsigned short* __restrict__ Mb,
    float* __restrict__ rs, int N, int ngroups, int nstripes) {
    int t = threadIdx.x;
    int wid = blockIdx.x * 4 + (t >> 6);
    int l = t & 63;
    int quad = l >> 4, col = l & 15;
    int dt = wid & 7;
    int stripe = wid >> 3;

    bf16x8 bw[4], bm[4];
    int wrow = (dt * 16 + col) * D;
#pragma unroll
    for (int ks = 0; ks < 4; ++ks) {
        int off = wrow + ks * 32 + quad * 8;
        bw[ks] = *(const bf16x8*)(Wb + off);
        bm[ks] = *(const bf16x8*)(Mb + off);
    }

    const bf16x8 zero8 = {0, 0, 0, 0, 0, 0, 0, 0};
    float vsum = 0.f;

    for (int grp = stripe; grp < ngroups; grp += nstripes) {
        int node = grp * 16 + col;
        bool valid = node < N;
        int nid = valid ? node_ids[node] : 0;
        const unsigned short* ar = aggb + (size_t)node * D + quad * 8;

        f32x4 acc = {0.f, 0.f, 0.f, 0.f};
#pragma unroll
        for (int ks = 0; ks < 4; ++ks) {
            bf16x8 ax;
            if (BF) {
                const unsigned short* xr =
                    (const unsigned short*)embv + (size_t)nid * D + quad * 8;
                ax = valid ? *(const bf16x8*)(xr + ks * 32) : zero8;
            } else {
                if (valid) {
                    const float4* xf = (const float4*)((const float*)embv +
                                       (size_t)nid * D + quad * 8 + ks * 32);
                    ushort4 p0 = pack4(xf[0]);
                    ushort4 p1 = pack4(xf[1]);
                    ax[0] = (short)p0.x; ax[1] = (short)p0.y;
                    ax[2] = (short)p0.z; ax[3] = (short)p0.w;
                    ax[4] = (short)p1.x; ax[5] = (short)p1.y;
                    ax[6] = (short)p1.z; ax[7] = (short)p1.w;
                } else ax = zero8;
            }
            bf16x8 aa = valid ? *(const bf16x8*)(ar + ks * 32) : zero8;
            acc = __builtin_amdgcn_mfma_f32_16x16x32_bf16(ax, bw[ks], acc, 0, 0, 0);
            acc = __builtin_amdgcn_mfma_f32_16x16x32_bf16(aa, bm[ks], acc, 0, 0, 0);
        }
        vsum += fmaxf(acc[0], 0.f) + fmaxf(acc[1], 0.f)
              + fmaxf(acc[2], 0.f) + fmaxf(acc[3], 0.f);
    }

    vsum += __shfl_xor(vsum, 16);
    vsum += __shfl_xor(vsum, 32);
    if (l < 16) atomicAdd(&rs[(dt * 16 + col) * RS_STRIDE], vsum);
}

// -------------------------------------------------------------------------
__global__ void softmax_kernel(const float* __restrict__ rs, float* __restrict__ out) {
    int t = threadIdx.x;                 // 0..63
    float v0 = rs[t * RS_STRIDE];
    float v1 = rs[(t + 64) * RS_STRIDE];
    float m = fmaxf(v0, v1);
    for (int o = 32; o > 0; o >>= 1) m = fmaxf(m, __shfl_xor(m, o));
    float e0 = expf(v0 - m);
    float e1 = expf(v1 - m);
    float s = e0 + e1;
    for (int o = 32; o > 0; o >>= 1) s += __shfl_xor(s, o);
    float inv = 1.0f / s;
    out[t] = e0 * inv;
    out[t + 64] = e1 * inv;
}

extern "C" void kernel_launch(void* const* d_in, const int* in_sizes, int n_in,
                              void* d_out, int out_size, void* d_ws, size_t ws_size,
                              hipStream_t stream) {
    const int*   node_ids = (const int*)d_in[0];
    const int*   nbr      = (const int*)d_in[1];
    const int*   seg      = (const int*)d_in[2];
    const float* W        = (const float*)d_in[3];
    const float* M        = (const float*)d_in[4];
    const float* emb      = (const float*)d_in[5];
    float* out = (float*)d_out;

    int N = in_sizes[0];
    int E = in_sizes[1];
    long long VD = in_sizes[5];          // V*D elements
    int ngroups  = (N + 15) / 16;

    // ws layout: aggb[N*D] u16 | Wb | Mb | rs fp32 | row_ptr int | embb[V*D] u16
    unsigned short* aggb = (unsigned short*)d_ws;
    unsigned short* Wb   = aggb + (size_t)N * D;
    unsigned short* Mb   = Wb + D * D;
    float* rs            = (float*)(Mb + D * D);
    int* row_ptr         = (int*)(rs + (size_t)D * RS_STRIDE);
    unsigned short* embb = (unsigned short*)(row_ptr + (N + 1));

    size_t need_bf = (size_t)(row_ptr + (N + 1) - (int*)d_ws) * 4 + (size_t)VD * 2;
    bool use_bf = ws_size >= need_bf;
    int n4 = use_bf ? (int)(VD / 4) : 0;
    int cvt_n = (n4 > 8192 ? n4 : 8192);
    int prep_n = (cvt_n > E ? cvt_n : E);

    prep_kernel<<<(prep_n + 255) / 256, 256, 0, stream>>>(emb, W, M, seg, embb, Wb, Mb,
                                                          rs, row_ptr, n4, E, N);
    if (use_bf) {
        fused_kernel<<<ngroups, 256, 0, stream>>>(node_ids, nbr, row_ptr, embb,
                                                  Wb, Mb, rs, N);
    } else {
        int nstripes = (ngroups + 1) / 2;
        agg_f32_kernel<<<(N + 3) / 4, 256, 0, stream>>>(nbr, row_ptr, emb, aggb, N);
        matvec_kernel<false><<<2 * nstripes, 256, 0, stream>>>(node_ids, emb, aggb, Wb, Mb,
                                                               rs, N, ngroups, nstripes);
    }
    softmax_kernel<<<1, 64, 0, stream>>>(rs, out);
}

// Round 2
// 141.856 us; speedup vs baseline: 1.0939x; 1.0763x over previous
//
#include <hip/hip_runtime.h>

#define D 128
#define RS_STRIDE 64      // floats (256 B) between result slots

typedef __attribute__((ext_vector_type(8))) short bf16x8;
typedef __attribute__((ext_vector_type(8))) unsigned short u16x8;
typedef __attribute__((ext_vector_type(4))) float f32x4;
typedef __attribute__((ext_vector_type(2))) float f32x2;

__device__ __forceinline__ unsigned short f2bf(float f) {
    unsigned u = __float_as_uint(f);
    unsigned r = (u + 0x7fffu + ((u >> 16) & 1u)) >> 16;
    return (unsigned short)r;
}
__device__ __forceinline__ float bf2f(unsigned short h) {
    return __uint_as_float(((unsigned)h) << 16);
}
__device__ __forceinline__ ushort4 pack4(float4 v) {
    ushort4 o; o.x = f2bf(v.x); o.y = f2bf(v.y); o.z = f2bf(v.z); o.w = f2bf(v.w);
    return o;
}
__device__ __forceinline__ void red3(float& x) {
    x += __shfl_xor(x, 8);
    x += __shfl_xor(x, 16);
    x += __shfl_xor(x, 32);
}
// fp8 e4m3 x4 (one dword) decode-accumulate into 4 fp32 slots (HW cvt).
__device__ __forceinline__ void acc4(unsigned v, float* s) {
    f32x2 lo = __builtin_amdgcn_cvt_pk_f32_fp8(v, false);
    f32x2 hi = __builtin_amdgcn_cvt_pk_f32_fp8(v, true);
    s[0] += lo[0]; s[1] += lo[1]; s[2] += hi[0]; s[3] += hi[1];
}
__device__ __forceinline__ void acc16(uint4 v, float* s) {
    acc4(v.x, s); acc4(v.y, s + 4); acc4(v.z, s + 8); acc4(v.w, s + 12);
}
// LDS tile swizzle: 16B slot s (0..15) of row r -> slot s^(r&7). Keeps the
// 16-row column-slice ds_read_b128 at 2-way (free) instead of 16-way conflict.
__device__ __forceinline__ int swz(int r, int s) {
    return r * D + ((s ^ (r & 7)) << 3);     // ushort index
}

// -------------------------------------------------------------------------
// Fused prep: emb fp32->fp8 e4m3 (if n4>0), W/M fp32->bf16, zero rs slots,
// and row_ptr[N+1] from sorted segment_ids.
__global__ void prep_kernel(const float* __restrict__ emb, const float* __restrict__ W,
                            const float* __restrict__ M, const int* __restrict__ seg,
                            unsigned char* __restrict__ emb8,
                            unsigned short* __restrict__ Wb, unsigned short* __restrict__ Mb,
                            float* __restrict__ rs, int* __restrict__ row_ptr,
                            int n4, int E, int N) {
    int i = blockIdx.x * blockDim.x + threadIdx.x;
    if (i < n4) {
        float4 v = ((const float4*)emb)[i];
        int p = __builtin_amdgcn_cvt_pk_fp8_f32(v.x, v.y, 0, false);
        p = __builtin_amdgcn_cvt_pk_fp8_f32(v.z, v.w, p, true);
        ((unsigned*)emb8)[i] = (unsigned)p;
    }
    if (i < 4096)       ((ushort4*)Wb)[i]        = pack4(((const float4*)W)[i]);
    else if (i < 8192)  ((ushort4*)Mb)[i - 4096] = pack4(((const float4*)M)[i - 4096]);
    if (i < D) rs[i * RS_STRIDE] = 0.0f;
    if (i < E) {
        int s = seg[i];
        if (i == 0) {
            for (int n = 0; n <= s; ++n) row_ptr[n] = 0;
        } else {
            int sp = seg[i - 1];
            for (int n = sp + 1; n <= s; ++n) row_ptr[n] = i;
        }
        if (i == E - 1) {
            for (int n = s + 1; n <= N; ++n) row_ptr[n] = E;
        }
    }
}

// -------------------------------------------------------------------------
// Fused segment-sum + MFMA matvec + relu + column-sum, fp8 gather edition.
// One block = one 16-node group. Phase A: wave w aggregates nodes 4w..4w+3:
// 8 edge streams (j) x 8 chunk lanes (c); lane owns 16 contiguous dims
// [16c,16c+16) = one uint4 (16 fp8) per edge, fp32 accum via v_cvt_pk_f32_fp8;
// writes agg + self rows as bf16 into swizzled LDS. Phase B: wave w computes
// dim-tiles {w, w+4}: X fragments from LDS once, W/M from global (L2-hot),
// 8 MFMAs/tile, relu, atomicAdd into rs.
// A-frag: A[m=lane&15][k=quad*8+j]; B[k][n=lane&15]=W[n][k]; C/D: col=dim,
// row=quad*4+reg (node).
__global__ __launch_bounds__(256) void fused_kernel(
    const int* __restrict__ node_ids, const int* __restrict__ nbr,
    const int* __restrict__ row_ptr, const unsigned char* __restrict__ emb8,
    const unsigned short* __restrict__ Wb, const unsigned short* __restrict__ Mb,
    float* __restrict__ rs, int N) {
    __shared__ unsigned short xs[16 * D];    // self-emb rows (bf16, swizzled)
    __shared__ unsigned short as_[16 * D];   // agg rows     (bf16, swizzled)

    int t = threadIdx.x;
    int w = t >> 6;          // wave 0..3
    int tt = t & 63;
    int g = blockIdx.x;      // node group

    {   // ---- Phase A: aggregate 4 nodes per wave ----
        int c = tt & 7;      // dim chunk: owns dims [16c, 16c+16)
        int j = tt >> 3;     // edge stream 0..7
        for (int i = 0; i < 4; ++i) {
            int r = w * 4 + i;           // local row 0..15
            int n = g * 16 + r;
            bool valid = n < N;

            // self row: issue early so it overlaps the edge loop
            uint4 xv = make_uint4(0u, 0u, 0u, 0u);   // fp8 0x00 == 0.0f
            if (valid && j == 0)
                xv = *(const uint4*)(emb8 + (size_t)node_ids[n] * D + c * 16);

            float s[16];
#pragma unroll
            for (int k = 0; k < 16; ++k) s[k] = 0.f;

            int lo = valid ? row_ptr[n] : 0;
            int hi = valid ? row_ptr[n + 1] : 0;
            int e = lo + j;
            for (; e + 8 < hi; e += 16) {        // 2 edges in flight per lane
                uint4 a = *(const uint4*)(emb8 + (size_t)nbr[e] * D + c * 16);
                uint4 b = *(const uint4*)(emb8 + (size_t)nbr[e + 8] * D + c * 16);
                acc16(a, s);
                acc16(b, s);
            }
            if (e < hi) {
                uint4 a = *(const uint4*)(emb8 + (size_t)nbr[e] * D + c * 16);
                acc16(a, s);
            }
#pragma unroll
            for (int k = 0; k < 16; ++k) red3(s[k]);

            if (j == 0) {
                u16x8 o0, o1;
#pragma unroll
                for (int k = 0; k < 8; ++k) { o0[k] = f2bf(s[k]); o1[k] = f2bf(s[k + 8]); }
                *(u16x8*)&as_[swz(r, 2 * c)]     = o0;
                *(u16x8*)&as_[swz(r, 2 * c + 1)] = o1;

                float x[16];
#pragma unroll
                for (int k = 0; k < 16; ++k) x[k] = 0.f;
                acc16(xv, x);
                u16x8 p0, p1;
#pragma unroll
                for (int k = 0; k < 8; ++k) { p0[k] = f2bf(x[k]); p1[k] = f2bf(x[k + 8]); }
                *(u16x8*)&xs[swz(r, 2 * c)]     = p0;
                *(u16x8*)&xs[swz(r, 2 * c + 1)] = p1;
            }
        }
    }
    __syncthreads();

    // ---- Phase B: matvec for dim-tiles {w, w+4} ----
    int quad = tt >> 4, col = tt & 15;
    bf16x8 ax[4], aa[4];
#pragma unroll
    for (int ks = 0; ks < 4; ++ks) {         // elements ks*32 + quad*8 .. +8
        ax[ks] = *(const bf16x8*)&xs[swz(col, ks * 4 + quad)];
        aa[ks] = *(const bf16x8*)&as_[swz(col, ks * 4 + quad)];
    }
#pragma unroll
    for (int p = 0; p < 2; ++p) {
        int dt = w + p * 4;
        int wrow = (dt * 16 + col) * D + quad * 8;
        f32x4 acc = {0.f, 0.f, 0.f, 0.f};
#pragma unroll
        for (int ks = 0; ks < 4; ++ks) {
            bf16x8 bw = *(const bf16x8*)(Wb + wrow + ks * 32);
            bf16x8 bm = *(const bf16x8*)(Mb + wrow + ks * 32);
            acc = __builtin_amdgcn_mfma_f32_16x16x32_bf16(ax[ks], bw, acc, 0, 0, 0);
            acc = __builtin_amdgcn_mfma_f32_16x16x32_bf16(aa[ks], bm, acc, 0, 0, 0);
        }
        float v = fmaxf(acc[0], 0.f) + fmaxf(acc[1], 0.f)
                + fmaxf(acc[2], 0.f) + fmaxf(acc[3], 0.f);
        v += __shfl_xor(v, 16);
        v += __shfl_xor(v, 32);
        if (tt < 16) atomicAdd(&rs[(dt * 16 + col) * RS_STRIDE], v);
    }
}

// -------------------------------------------------------------------------
// Fallback path (ws too small for fp8 emb table): proven fp32 kernels.
__global__ void agg_f32_kernel(const int* __restrict__ nbr, const int* __restrict__ row_ptr,
                               const float* __restrict__ emb,
                               unsigned short* __restrict__ aggb, int N) {
    int n = blockIdx.x * 4 + (threadIdx.x >> 6);
    if (n >= N) return;
    int tt = threadIdx.x & 63;
    int c = tt & 7;
    int j = tt >> 3;

    int lo = row_ptr[n], hi = row_ptr[n + 1];

    float4 s0 = make_float4(0.f, 0.f, 0.f, 0.f);
    float4 s1 = make_float4(0.f, 0.f, 0.f, 0.f);
    float4 s2 = make_float4(0.f, 0.f, 0.f, 0.f);
    float4 s3 = make_float4(0.f, 0.f, 0.f, 0.f);
    for (int e = lo + j; e < hi; e += 8) {
        const float4* r = (const float4*)&emb[(size_t)nbr[e] * D];
        float4 v0 = r[c], v1 = r[c + 8], v2 = r[c + 16], v3 = r[c + 24];
        s0.x += v0.x; s0.y += v0.y; s0.z += v0.z; s0.w += v0.w;
        s1.x += v1.x; s1.y += v1.y; s1.z += v1.z; s1.w += v1.w;
        s2.x += v2.x; s2.y += v2.y; s2.z += v2.z; s2.w += v2.w;
        s3.x += v3.x; s3.y += v3.y; s3.z += v3.z; s3.w += v3.w;
    }
    red3(s0.x); red3(s0.y); red3(s0.z); red3(s0.w);
    red3(s1.x); red3(s1.y); red3(s1.z); red3(s1.w);
    red3(s2.x); red3(s2.y); red3(s2.z); red3(s2.w);
    red3(s3.x); red3(s3.y); red3(s3.z); red3(s3.w);
    if (j == 0) {
        ushort4* o = (ushort4*)(aggb + (size_t)n * D);
        o[c]      = pack4(s0);
        o[c + 8]  = pack4(s1);
        o[c + 16] = pack4(s2);
        o[c + 24] = pack4(s3);
    }
}

__global__ __launch_bounds__(256) void matvec_f32_kernel(
    const int* __restrict__ node_ids, const float* __restrict__ emb,
    const unsigned short* __restrict__ aggb,
    const unsigned short* __restrict__ Wb, const unsigned short* __restrict__ Mb,
    float* __restrict__ rs, int N, int ngroups, int nstripes) {
    int t = threadIdx.x;
    int wid = blockIdx.x * 4 + (t >> 6);
    int l = t & 63;
    int quad = l >> 4, col = l & 15;
    int dt = wid & 7;
    int stripe = wid >> 3;

    bf16x8 bw[4], bm[4];
    int wrow = (dt * 16 + col) * D;
#pragma unroll
    for (int ks = 0; ks < 4; ++ks) {
        int off = wrow + ks * 32 + quad * 8;
        bw[ks] = *(const bf16x8*)(Wb + off);
        bm[ks] = *(const bf16x8*)(Mb + off);
    }

    const bf16x8 zero8 = {0, 0, 0, 0, 0, 0, 0, 0};
    float vsum = 0.f;

    for (int grp = stripe; grp < ngroups; grp += nstripes) {
        int node = grp * 16 + col;
        bool valid = node < N;
        int nid = valid ? node_ids[node] : 0;
        const unsigned short* ar = aggb + (size_t)node * D + quad * 8;

        f32x4 acc = {0.f, 0.f, 0.f, 0.f};
#pragma unroll
        for (int ks = 0; ks < 4; ++ks) {
            bf16x8 ax;
            if (valid) {
                const float4* xf = (const float4*)(emb +
                                   (size_t)nid * D + quad * 8 + ks * 32);
                ushort4 p0 = pack4(xf[0]);
                ushort4 p1 = pack4(xf[1]);
                ax[0] = (short)p0.x; ax[1] = (short)p0.y;
                ax[2] = (short)p0.z; ax[3] = (short)p0.w;
                ax[4] = (short)p1.x; ax[5] = (short)p1.y;
                ax[6] = (short)p1.z; ax[7] = (short)p1.w;
            } else ax = zero8;
            bf16x8 aa = valid ? *(const bf16x8*)(ar + ks * 32) : zero8;
            acc = __builtin_amdgcn_mfma_f32_16x16x32_bf16(ax, bw[ks], acc, 0, 0, 0);
            acc = __builtin_amdgcn_mfma_f32_16x16x32_bf16(aa, bm[ks], acc, 0, 0, 0);
        }
        vsum += fmaxf(acc[0], 0.f) + fmaxf(acc[1], 0.f)
              + fmaxf(acc[2], 0.f) + fmaxf(acc[3], 0.f);
    }

    vsum += __shfl_xor(vsum, 16);
    vsum += __shfl_xor(vsum, 32);
    if (l < 16) atomicAdd(&rs[(dt * 16 + col) * RS_STRIDE], vsum);
}

// -------------------------------------------------------------------------
__global__ void softmax_kernel(const float* __restrict__ rs, float* __restrict__ out) {
    int t = threadIdx.x;                 // 0..63
    float v0 = rs[t * RS_STRIDE];
    float v1 = rs[(t + 64) * RS_STRIDE];
    float m = fmaxf(v0, v1);
    for (int o = 32; o > 0; o >>= 1) m = fmaxf(m, __shfl_xor(m, o));
    float e0 = expf(v0 - m);
    float e1 = expf(v1 - m);
    float s = e0 + e1;
    for (int o = 32; o > 0; o >>= 1) s += __shfl_xor(s, o);
    float inv = 1.0f / s;
    out[t] = e0 * inv;
    out[t + 64] = e1 * inv;
}

extern "C" void kernel_launch(void* const* d_in, const int* in_sizes, int n_in,
                              void* d_out, int out_size, void* d_ws, size_t ws_size,
                              hipStream_t stream) {
    const int*   node_ids = (const int*)d_in[0];
    const int*   nbr      = (const int*)d_in[1];
    const int*   seg      = (const int*)d_in[2];
    const float* W        = (const float*)d_in[3];
    const float* M        = (const float*)d_in[4];
    const float* emb      = (const float*)d_in[5];
    float* out = (float*)d_out;

    int N = in_sizes[0];
    int E = in_sizes[1];
    long long VD = in_sizes[5];          // V*D elements
    int ngroups  = (N + 15) / 16;

    // ws layout: aggb[N*D] u16 | Wb | Mb | rs fp32 | row_ptr int | emb8[VD] u8
    unsigned short* aggb = (unsigned short*)d_ws;
    unsigned short* Wb   = aggb + (size_t)N * D;
    unsigned short* Mb   = Wb + D * D;
    float* rs            = (float*)(Mb + D * D);
    int* row_ptr         = (int*)(rs + (size_t)D * RS_STRIDE);
    unsigned char* emb8  = (unsigned char*)(row_ptr + (N + 1));

    size_t need_fp8 = (size_t)((char*)emb8 - (char*)d_ws) + (size_t)VD;
    bool use_fp8 = ws_size >= need_fp8;
    int n4 = use_fp8 ? (int)(VD / 4) : 0;
    int cvt_n = (n4 > 8192 ? n4 : 8192);
    int prep_n = (cvt_n > E ? cvt_n : E);

    prep_kernel<<<(prep_n + 255) / 256, 256, 0, stream>>>(emb, W, M, seg, emb8, Wb, Mb,
                                                          rs, row_ptr, n4, E, N);
    if (use_fp8) {
        fused_kernel<<<ngroups, 256, 0, stream>>>(node_ids, nbr, row_ptr, emb8,
                                                  Wb, Mb, rs, N);
    } else {
        int nstripes = (ngroups + 1) / 2;
        agg_f32_kernel<<<(N + 3) / 4, 256, 0, stream>>>(nbr, row_ptr, emb, aggb, N);
        matvec_f32_kernel<<<2 * nstripes, 256, 0, stream>>>(node_ids, emb, aggb, Wb, Mb,
                                                            rs, N, ngroups, nstripes);
    }
    softmax_kernel<<<1, 64, 0, stream>>>(rs, out);
}